// Round 8
// baseline (379.907 us; speedup 1.0000x reference)
//
#include <hip/hip_runtime.h>
#include <hip/hip_bf16.h>
#include <math.h>

#define BATCH 8
#define NPTS 4096
#define CH 128
#define NTILEBLOCKS (32 * 32 * BATCH)   // tile_kernel grid size (8192)

// exp(s/TEMP) = 2^(s * 10 * log2(e)). sqrt(10/ln2) is folded into the
// normalize scale so the GEMM accumulator is already the exp2 argument.
#define SQRT_TEMP_LOG2E 3.79828256f   // sqrt(14.4269504089)

typedef __attribute__((ext_vector_type(4))) float f32x4;
typedef __attribute__((ext_vector_type(4))) int   i32x4;
typedef __attribute__((ext_vector_type(8))) short bf16x8;

typedef __attribute__((address_space(3))) unsigned int lds_uint;
typedef __attribute__((address_space(1))) const unsigned int gbl_uint;

__device__ __forceinline__ void load_lds16(const void* g, const void* l) {
    __builtin_amdgcn_global_load_lds((gbl_uint*)g, (lds_uint*)l, 16, 0, 0);
}

// v_exp_f32 is 2^x. (__exp2f collides with a glibc math.h macro.)
__device__ __forceinline__ float fast_exp2(float x) {
    return __builtin_amdgcn_exp2f(x);
}

// ---------------------------------------------------------------------------
// Kernel 1: one-pass L2-normalize (4 threads/point, 32 ch each in registers),
// zero pos/neg and the completion counter.
// ---------------------------------------------------------------------------
__global__ __launch_bounds__(256) void normalize_kernel(
    const float* __restrict__ f, __hip_bfloat16* __restrict__ vn,
    float* __restrict__ pos, float* __restrict__ neg, int* __restrict__ counter)
{
    int idx = blockIdx.x * 256 + threadIdx.x;   // 0 .. 131071
    int point = idx >> 2, q = idx & 3;
    int b = point >> 12, n = point & (NPTS - 1);
    const float* base = f + (size_t)b * CH * NPTS + (size_t)(q * 32) * NPTS + n;

    float x[32];
    float ss = 0.0f;
    #pragma unroll
    for (int c = 0; c < 32; c++) {
        x[c] = base[(size_t)c * NPTS];
        ss += x[c] * x[c];
    }
    ss += __shfl_xor(ss, 1);
    ss += __shfl_xor(ss, 2);    // 4 lanes of one point share ss
    float scale = SQRT_TEMP_LOG2E / fmaxf(sqrtf(ss), 1e-12f);

    __hip_bfloat16* out = vn + (size_t)point * CH + q * 32;
    #pragma unroll
    for (int c0 = 0; c0 < 32; c0 += 8) {
        union { __hip_bfloat16 h[8]; uint4 u; } pk;
        #pragma unroll
        for (int j = 0; j < 8; j++)
            pk.h[j] = __float2bfloat16(x[c0 + j] * scale);
        *((uint4*)(out + c0)) = pk.u;
    }
    if (q == 0) pos[point] = 0.0f;
    else if (q == 1) neg[point] = 0.0f;
    if (idx == 0) *counter = 0;
}

// ---------------------------------------------------------------------------
// Kernel 2: R6 structure (128x128 tile, 16x16x32 swapped-operand MFMA,
// 8192-block grid) but 4 waves/block with each wave owning 32 rows as two
// 16-row blocks: every bfrag ds_read feeds TWO MFMAs -> per-block LDS reads
// halve (256->128 KB). R7's lesson: keep blocks plentiful and chains short
// (16 independent acc chains x 4 deep; R7's 4x8-deep at 1.5 blocks/CU was
// latency-bound at 165 us).
//
// Swapped operands: mfma(bfrag, afrag, acc) puts S-row on lane&15 (in-lane
// reduction) and S-col on quad*4+reg.
//
// launch_bounds(256,4): 4 blocks/CU, 128-reg cap; usage ~= 64 AGPR(acc) +
// ~56 VGPR = ~120. WRITE_SIZE is the spill tripwire (R4: 178 MB explosion).
// ---------------------------------------------------------------------------
__global__ __launch_bounds__(256, 4) void tile_kernel(
    const __hip_bfloat16* __restrict__ vn, const int* __restrict__ labels,
    float* __restrict__ pos, float* __restrict__ neg,
    int* __restrict__ counter, float* __restrict__ out)
{
    __shared__ short lB[128 * CH];   // 32 KB: the 128 cols of S, row-major
    __shared__ int labC[128];
    __shared__ int lastFlag;
    __shared__ float red[4];

    const int b  = blockIdx.z;
    const int rt = blockIdx.y, ct = blockIdx.x;
    const bool diag = (rt == ct);

    const int tid = threadIdx.x;
    const int w = tid >> 6, lane = tid & 63;
    const int lane15 = lane & 15, quad = lane >> 4;

    const int row0 = rt * 128, col0 = ct * 128;
    const __hip_bfloat16* vb = vn + (size_t)b * NPTS * CH;

    if (tid < 128) labC[tid] = labels[b * NPTS + col0 + tid];

    // Stage B-tile -> LDS via global_load_lds, XOR chunk swizzle at the
    // global source (LDS dest order is HW-fixed: wave-uniform base +
    // lane*16B; lane l -> row base+quad, chunk lane15). 4 waves x 8 iters
    // x 4 rows = 128 rows. R1..R7: SQ_LDS_BANK_CONFLICT == 0.
    {
        const __hip_bfloat16* Bb = vb + (size_t)col0 * CH;
        #pragma unroll
        for (int i = 0; i < 8; i++) {
            int ldsrow = (w * 8 + i) * 4;           // wave-uniform
            int r = ldsrow + quad;                  // row this lane feeds
            int g = lane15 ^ (r & 15);              // swizzled global chunk
            load_lds16(Bb + (size_t)r * CH + g * 8, &lB[ldsrow * CH]);
        }
    }

    // A-fragments direct from global for this wave's TWO 16-row blocks:
    // afrag[mi][ks] supplies (as MFMA B-operand) S-row = w*32+mi*16+lane15,
    // k = ks*32 + quad*8 + j. Issued pre-barrier; the vmcnt drain hides them.
    bf16x8 afrag[2][4];
    int lr[2];
    #pragma unroll
    for (int mi = 0; mi < 2; mi++) {
        const int row_l = w * 32 + mi * 16 + lane15;
        const __hip_bfloat16* Arow = vb + (size_t)(row0 + row_l) * CH;
        #pragma unroll
        for (int ks = 0; ks < 4; ks++)
            afrag[mi][ks] = *(const bf16x8*)(Arow + (ks * 4 + quad) * 8);
        lr[mi] = labels[b * NPTS + row0 + row_l];
    }

    __syncthreads();   // drains vmcnt (incl. global_load_lds)

    // MFMA: each bfrag read feeds both row-blocks. 16 independent chains,
    // 4 deep. acc[mi][ni] element (lane,r) = S[row0+w*32+mi*16+lane15]
    //                                         [col0+ni*16+quad*4+r].
    f32x4 acc[2][8] = {};
    #pragma unroll
    for (int ks = 0; ks < 4; ks++) {
        const int koff = ((ks * 4 + quad) ^ lane15) << 3;   // swizzled, shorts
        #pragma unroll
        for (int ni = 0; ni < 8; ni++) {
            bf16x8 bf = *(const bf16x8*)&lB[(ni * 16 + lane15) * CH + koff];
            acc[0][ni] = __builtin_amdgcn_mfma_f32_16x16x32_bf16(
                bf, afrag[0][ks], acc[0][ni], 0, 0, 0);
            acc[1][ni] = __builtin_amdgcn_mfma_f32_16x16x32_bf16(
                bf, afrag[1][ks], acc[1][ni], 0, 0, 0);
        }
    }

    // Epilogue: in-lane over each row-block's 32 elements, fold quads,
    // 2 atomics per row.
    #pragma unroll
    for (int mi = 0; mi < 2; mi++) {
        const int row_l = w * 32 + mi * 16 + lane15;
        float p = 0.0f, tt = 0.0f;
        if (diag) {
            #pragma unroll
            for (int ni = 0; ni < 8; ni++) {
                const bool dblk = (ni * 16 == w * 32 + mi * 16);  // wave-unif
                const i32x4 lc = *(const i32x4*)&labC[ni * 16 + quad * 4];
                #pragma unroll
                for (int r = 0; r < 4; r++) {
                    float e = fast_exp2(acc[mi][ni][r]);
                    if (dblk && lane15 == quad * 4 + r) e = 0.0f; // diagonal
                    tt += e;
                    p  += (lc[r] == lr[mi]) ? e : 0.0f;
                }
            }
        } else {
            #pragma unroll
            for (int ni = 0; ni < 8; ni++) {
                const i32x4 lc = *(const i32x4*)&labC[ni * 16 + quad * 4];
                #pragma unroll
                for (int r = 0; r < 4; r++) {
                    float e = fast_exp2(acc[mi][ni][r]);
                    tt += e;
                    p  += (lc[r] == lr[mi]) ? e : 0.0f;
                }
            }
        }
        p  += __shfl_xor(p, 16);   p  += __shfl_xor(p, 32);
        tt += __shfl_xor(tt, 16);  tt += __shfl_xor(tt, 32);
        if (lane < 16) {
            atomicAdd(&pos[b * NPTS + row0 + row_l], p);
            atomicAdd(&neg[b * NPTS + row0 + row_l], tt - p);
        }
    }

    // --- Fused finalize: last block reduces log((p+n)/p) and writes out. ---
    __syncthreads();                 // all waves' atomics drained (vmcnt 0)
    if (tid == 0) {
        __threadfence();             // order our atomics before the bump
        int c = atomicAdd(counter, 1);
        lastFlag = (c == NTILEBLOCKS - 1);
    }
    __syncthreads();
    if (lastFlag) {
        __threadfence();
        volatile const float* vp = pos;
        volatile const float* vq = neg;
        float acc2 = 0.0f;
        for (int i = tid; i < BATCH * NPTS; i += 256) {
            float pp = vp[i], qq = vq[i];
            acc2 += __logf((pp + qq) / pp);    // == -log(p/(p+n))
        }
        #pragma unroll
        for (int off = 32; off; off >>= 1) acc2 += __shfl_down(acc2, off);
        if (lane == 0) red[w] = acc2;
        __syncthreads();
        if (tid < 4) {
            float v = red[tid];
            v += __shfl_down(v, 2);
            v += __shfl_down(v, 1);
            if (tid == 0) out[0] = v * (1.0f / (BATCH * NPTS));
        }
    }
}

extern "C" void kernel_launch(void* const* d_in, const int* in_sizes, int n_in,
                              void* d_out, int out_size, void* d_ws, size_t ws_size,
                              hipStream_t stream)
{
    const float* features = (const float*)d_in[0];
    const int*   labels   = (const int*)d_in[1];
    float*       out      = (float*)d_out;

    // Workspace: vn bf16 [8][4096][128] = 8 MB, pos/neg fp32, counter.
    __hip_bfloat16* vn = (__hip_bfloat16*)d_ws;
    float* pos = (float*)((char*)d_ws + (size_t)BATCH * NPTS * CH * sizeof(__hip_bfloat16));
    float* neg = pos + BATCH * NPTS;
    int* counter = (int*)(neg + BATCH * NPTS);

    hipLaunchKernelGGL(normalize_kernel, dim3(BATCH * NPTS * 4 / 256), dim3(256), 0, stream,
                       features, vn, pos, neg, counter);
    // Full tile grid: 32x32 tiles x 8 batches = 8192 blocks, 256 threads.
    hipLaunchKernelGGL(tile_kernel, dim3(32, 32, BATCH), dim3(256), 0, stream,
                       vn, labels, pos, neg, counter, out);
}

// Round 9
// 127.510 us; speedup vs baseline: 2.9794x; 2.9794x over previous
//
#include <hip/hip_runtime.h>
#include <hip/hip_bf16.h>
#include <math.h>

#define BATCH 8
#define NPTS 4096
#define CH 128

// exp(s/TEMP) = 2^(s * 10 * log2(e)). sqrt(10/ln2) is folded into the
// normalize scale so the GEMM accumulator is already the exp2 argument.
#define SQRT_TEMP_LOG2E 3.79828256f   // sqrt(14.4269504089)

typedef __attribute__((ext_vector_type(4))) float f32x4;
typedef __attribute__((ext_vector_type(4))) int   i32x4;
typedef __attribute__((ext_vector_type(8))) short bf16x8;

typedef __attribute__((address_space(3))) unsigned int lds_uint;
typedef __attribute__((address_space(1))) const unsigned int gbl_uint;

__device__ __forceinline__ void load_lds16(const void* g, const void* l) {
    __builtin_amdgcn_global_load_lds((gbl_uint*)g, (lds_uint*)l, 16, 0, 0);
}

// v_exp_f32 is 2^x. (__exp2f collides with a glibc math.h macro.)
__device__ __forceinline__ float fast_exp2(float x) {
    return __builtin_amdgcn_exp2f(x);
}

// ---------------------------------------------------------------------------
// Kernel 1: one-pass L2-normalize (4 threads/point, 32 ch each in registers),
// zero pos/neg.
// ---------------------------------------------------------------------------
__global__ __launch_bounds__(256) void normalize_kernel(
    const float* __restrict__ f, __hip_bfloat16* __restrict__ vn,
    float* __restrict__ pos, float* __restrict__ neg)
{
    int idx = blockIdx.x * 256 + threadIdx.x;   // 0 .. 131071
    int point = idx >> 2, q = idx & 3;
    int b = point >> 12, n = point & (NPTS - 1);
    const float* base = f + (size_t)b * CH * NPTS + (size_t)(q * 32) * NPTS + n;

    float x[32];
    float ss = 0.0f;
    #pragma unroll
    for (int c = 0; c < 32; c++) {
        x[c] = base[(size_t)c * NPTS];
        ss += x[c] * x[c];
    }
    ss += __shfl_xor(ss, 1);
    ss += __shfl_xor(ss, 2);    // 4 lanes of one point share ss
    float scale = SQRT_TEMP_LOG2E / fmaxf(sqrtf(ss), 1e-12f);

    __hip_bfloat16* out = vn + (size_t)point * CH + q * 32;
    #pragma unroll
    for (int c0 = 0; c0 < 32; c0 += 8) {
        union { __hip_bfloat16 h[8]; uint4 u; } pk;
        #pragma unroll
        for (int j = 0; j < 8; j++)
            pk.h[j] = __float2bfloat16(x[c0 + j] * scale);
        *((uint4*)(out + c0)) = pk.u;
    }
    if (q == 0) pos[point] = 0.0f;
    else if (q == 1) neg[point] = 0.0f;
}

// ---------------------------------------------------------------------------
// Kernel 2: 128x128 tile, 16x16x32 swapped-operand MFMA, 8192-block grid,
// 4 waves/block with each wave owning 32 rows as two 16-row blocks so every
// bfrag ds_read feeds TWO MFMAs (half of R6's LDS read traffic).
//
// NO fused finalize: R7/R8 proved the per-block __threadfence + one-address
// counter atomic serializes ~40 ns x nblocks (R7 166 us @4096, R8 320 us
// @8192, all pipes <10%) — device-scope fences per block are poison on
// non-coherent-XCD hardware. Separate finalize kernel instead.
//
// Swapped operands: mfma(bfrag, afrag, acc) puts S-row on lane&15 (in-lane
// reduction) and S-col on quad*4+reg.
//
// launch_bounds(256,4): 128-reg cap; usage ~= 64 AGPR(acc) + ~56 VGPR.
// WRITE_SIZE is the spill tripwire (R4: 178 MB explosion).
// ---------------------------------------------------------------------------
__global__ __launch_bounds__(256, 4) void tile_kernel(
    const __hip_bfloat16* __restrict__ vn, const int* __restrict__ labels,
    float* __restrict__ pos, float* __restrict__ neg)
{
    __shared__ short lB[128 * CH];   // 32 KB: the 128 cols of S, row-major
    __shared__ int labC[128];

    const int b  = blockIdx.z;
    const int rt = blockIdx.y, ct = blockIdx.x;
    const bool diag = (rt == ct);

    const int tid = threadIdx.x;
    const int w = tid >> 6, lane = tid & 63;
    const int lane15 = lane & 15, quad = lane >> 4;

    const int row0 = rt * 128, col0 = ct * 128;
    const __hip_bfloat16* vb = vn + (size_t)b * NPTS * CH;

    if (tid < 128) labC[tid] = labels[b * NPTS + col0 + tid];

    // Stage B-tile -> LDS via global_load_lds, XOR chunk swizzle at the
    // global source (LDS dest order is HW-fixed: wave-uniform base +
    // lane*16B; lane l -> row base+quad, chunk lane15). 4 waves x 8 iters
    // x 4 rows = 128 rows. R1..R8: SQ_LDS_BANK_CONFLICT == 0.
    {
        const __hip_bfloat16* Bb = vb + (size_t)col0 * CH;
        #pragma unroll
        for (int i = 0; i < 8; i++) {
            int ldsrow = (w * 8 + i) * 4;           // wave-uniform
            int r = ldsrow + quad;                  // row this lane feeds
            int g = lane15 ^ (r & 15);              // swizzled global chunk
            load_lds16(Bb + (size_t)r * CH + g * 8, &lB[ldsrow * CH]);
        }
    }

    // A-fragments direct from global for this wave's TWO 16-row blocks:
    // afrag[mi][ks] supplies (as MFMA B-operand) S-row = w*32+mi*16+lane15,
    // k = ks*32 + quad*8 + j. Issued pre-barrier; the vmcnt drain hides them.
    bf16x8 afrag[2][4];
    int lr[2];
    #pragma unroll
    for (int mi = 0; mi < 2; mi++) {
        const int row_l = w * 32 + mi * 16 + lane15;
        const __hip_bfloat16* Arow = vb + (size_t)(row0 + row_l) * CH;
        #pragma unroll
        for (int ks = 0; ks < 4; ks++)
            afrag[mi][ks] = *(const bf16x8*)(Arow + (ks * 4 + quad) * 8);
        lr[mi] = labels[b * NPTS + row0 + row_l];
    }

    __syncthreads();   // drains vmcnt (incl. global_load_lds)

    // MFMA: each bfrag read feeds both row-blocks. 16 independent chains,
    // 4 deep. acc[mi][ni] element (lane,r) = S[row0+w*32+mi*16+lane15]
    //                                         [col0+ni*16+quad*4+r].
    f32x4 acc[2][8] = {};
    #pragma unroll
    for (int ks = 0; ks < 4; ks++) {
        const int koff = ((ks * 4 + quad) ^ lane15) << 3;   // swizzled, shorts
        #pragma unroll
        for (int ni = 0; ni < 8; ni++) {
            bf16x8 bf = *(const bf16x8*)&lB[(ni * 16 + lane15) * CH + koff];
            acc[0][ni] = __builtin_amdgcn_mfma_f32_16x16x32_bf16(
                bf, afrag[0][ks], acc[0][ni], 0, 0, 0);
            acc[1][ni] = __builtin_amdgcn_mfma_f32_16x16x32_bf16(
                bf, afrag[1][ks], acc[1][ni], 0, 0, 0);
        }
    }

    // Epilogue: in-lane over each row-block's 32 elements, fold quads,
    // 2 atomics per row.
    #pragma unroll
    for (int mi = 0; mi < 2; mi++) {
        const int row_l = w * 32 + mi * 16 + lane15;
        float p = 0.0f, tt = 0.0f;
        if (diag) {
            #pragma unroll
            for (int ni = 0; ni < 8; ni++) {
                const bool dblk = (ni * 16 == w * 32 + mi * 16);  // wave-unif
                const i32x4 lc = *(const i32x4*)&labC[ni * 16 + quad * 4];
                #pragma unroll
                for (int r = 0; r < 4; r++) {
                    float e = fast_exp2(acc[mi][ni][r]);
                    if (dblk && lane15 == quad * 4 + r) e = 0.0f; // diagonal
                    tt += e;
                    p  += (lc[r] == lr[mi]) ? e : 0.0f;
                }
            }
        } else {
            #pragma unroll
            for (int ni = 0; ni < 8; ni++) {
                const i32x4 lc = *(const i32x4*)&labC[ni * 16 + quad * 4];
                #pragma unroll
                for (int r = 0; r < 4; r++) {
                    float e = fast_exp2(acc[mi][ni][r]);
                    tt += e;
                    p  += (lc[r] == lr[mi]) ? e : 0.0f;
                }
            }
        }
        p  += __shfl_xor(p, 16);   p  += __shfl_xor(p, 32);
        tt += __shfl_xor(tt, 16);  tt += __shfl_xor(tt, 32);
        if (lane < 16) {
            atomicAdd(&pos[b * NPTS + row0 + row_l], p);
            atomicAdd(&neg[b * NPTS + row0 + row_l], tt - p);
        }
    }
}

// ---------------------------------------------------------------------------
// Kernel 3: mean of log((p+n)/p) over 32768 rows. Single block, 1024 thr.
// ---------------------------------------------------------------------------
__global__ __launch_bounds__(1024) void finalize_kernel(
    const float* __restrict__ pos, const float* __restrict__ neg,
    float* __restrict__ out)
{
    float acc = 0.0f;
    for (int i = threadIdx.x; i < BATCH * NPTS; i += 1024) {
        float p = pos[i];
        float t = p + neg[i];
        acc += __logf(t / p);   // == -log(p / (p+n))
    }
    #pragma unroll
    for (int off = 32; off; off >>= 1) acc += __shfl_down(acc, off);
    __shared__ float red[16];
    if ((threadIdx.x & 63) == 0) red[threadIdx.x >> 6] = acc;
    __syncthreads();
    if (threadIdx.x < 16) {
        float v = red[threadIdx.x];
        #pragma unroll
        for (int off = 8; off; off >>= 1) v += __shfl_down(v, off);
        if (threadIdx.x == 0) out[0] = v * (1.0f / (BATCH * NPTS));
    }
}

extern "C" void kernel_launch(void* const* d_in, const int* in_sizes, int n_in,
                              void* d_out, int out_size, void* d_ws, size_t ws_size,
                              hipStream_t stream)
{
    const float* features = (const float*)d_in[0];
    const int*   labels   = (const int*)d_in[1];
    float*       out      = (float*)d_out;

    // Workspace: vn bf16 [8][4096][128] = 8 MB, then pos/neg fp32.
    __hip_bfloat16* vn = (__hip_bfloat16*)d_ws;
    float* pos = (float*)((char*)d_ws + (size_t)BATCH * NPTS * CH * sizeof(__hip_bfloat16));
    float* neg = pos + BATCH * NPTS;

    hipLaunchKernelGGL(normalize_kernel, dim3(BATCH * NPTS * 4 / 256), dim3(256), 0, stream,
                       features, vn, pos, neg);
    // Full tile grid: 32x32 tiles x 8 batches = 8192 blocks, 256 threads.
    hipLaunchKernelGGL(tile_kernel, dim3(32, 32, BATCH), dim3(256), 0, stream,
                       vn, labels, pos, neg);
    hipLaunchKernelGGL(finalize_kernel, dim3(1), dim3(1024), 0, stream, pos, neg, out);
}